// Round 2
// baseline (768.621 us; speedup 1.0000x reference)
//
#include <hip/hip_runtime.h>
#include <hip/hip_bf16.h>

#define N_NODES 40000
#define N_EDGES 640000
#define HIDDEN  128
#define NUM_RBF 50

typedef __attribute__((ext_vector_type(8))) short bf16x8;
typedef __attribute__((ext_vector_type(4))) float f32x4;

__device__ __forceinline__ short f2bf(float f) {
  __hip_bfloat16 h = __float2bfloat16(f);
  return (short)__builtin_bit_cast(unsigned short, h);
}
__device__ __forceinline__ float bf2f(unsigned short u) {
  unsigned int v = ((unsigned int)u) << 16;
  return __builtin_bit_cast(float, v);
}

__device__ __forceinline__ float fast_tanh(float x) {
  float e = __expf(2.0f * x);
  return 1.0f - 2.0f * __builtin_amdgcn_rcpf(e + 1.0f);
}

__device__ __forceinline__ f32x4 mfma16(bf16x8 a, bf16x8 b, f32x4 c) {
  return __builtin_amdgcn_mfma_f32_16x16x32_bf16(a, b, c, 0, 0, 0);
}

__device__ __forceinline__ bf16x8 load8_f32_bf16(const float* p) {
  const float4 v0 = ((const float4*)p)[0];
  const float4 v1 = ((const float4*)p)[1];
  bf16x8 r;
  r[0] = f2bf(v0.x); r[1] = f2bf(v0.y); r[2] = f2bf(v0.z); r[3] = f2bf(v0.w);
  r[4] = f2bf(v1.x); r[5] = f2bf(v1.y); r[6] = f2bf(v1.z); r[7] = f2bf(v1.w);
  return r;
}

// ---------------- CSR build ----------------
__global__ __launch_bounds__(256) void hist_kernel(const int* __restrict__ ei,
                                                   int* __restrict__ hist) {
  int e = blockIdx.x * 256 + threadIdx.x;
  if (e < N_EDGES) atomicAdd(&hist[ei[N_EDGES + e]], 1);
}

__global__ __launch_bounds__(256) void scan_kernel(const int* __restrict__ hist,
                                                   int* __restrict__ row_start,
                                                   int* __restrict__ cursor) {
  __shared__ int ls[256];
  const int tid = threadIdx.x;
  const int CH = (N_NODES + 255) / 256;  // 157
  const int base = tid * CH;
  int s = 0;
  for (int i = 0; i < CH; ++i) {
    int idx = base + i;
    if (idx < N_NODES) s += hist[idx];
  }
  ls[tid] = s;
  __syncthreads();
  for (int off = 1; off < 256; off <<= 1) {
    int t = (tid >= off) ? ls[tid - off] : 0;
    __syncthreads();
    ls[tid] += t;
    __syncthreads();
  }
  int run = ls[tid] - s;  // exclusive prefix
  for (int i = 0; i < CH; ++i) {
    int idx = base + i;
    if (idx < N_NODES) {
      int hv = hist[idx];
      row_start[idx] = run;
      cursor[idx] = run;
      run += hv;
    }
  }
  if (tid == 255) row_start[N_NODES] = run;
}

// ---------------- kernel 1: h = x @ W_in ----------------
__global__ __launch_bounds__(256) void hproj_kernel(
    const float* __restrict__ x, const float* __restrict__ W_in,
    float* __restrict__ h)
{
  __shared__ __align__(16) unsigned short sWt[128 * 136];
  const int tid = threadIdx.x, wave = tid >> 6, lane = tid & 63;
  const int ln = lane & 15, grp = lane >> 4;
  const int r0 = blockIdx.x * 64;

  for (int idx = tid; idx < 128 * 128; idx += 256) {
    int k = idx >> 7, c = idx & 127;
    sWt[c * 136 + k] = f2bf(W_in[idx]);
  }
  __syncthreads();

  const size_t r = (size_t)r0 + wave * 16 + ln;
  f32x4 acc[8];
#pragma unroll
  for (int ct = 0; ct < 8; ++ct) acc[ct] = (f32x4){0.f, 0.f, 0.f, 0.f};
#pragma unroll
  for (int ks = 0; ks < 4; ++ks) {
    bf16x8 a = load8_f32_bf16(&x[r * 128 + ks * 32 + grp * 8]);
#pragma unroll
    for (int ct = 0; ct < 8; ++ct) {
      bf16x8 b = *(const bf16x8*)&sWt[(ct * 16 + ln) * 136 + ks * 32 + grp * 8];
      acc[ct] = mfma16(a, b, acc[ct]);
    }
  }
#pragma unroll
  for (int ct = 0; ct < 8; ++ct) {
#pragma unroll
    for (int i = 0; i < 4; ++i) {
      h[(size_t)(r0 + wave * 16 + grp * 4 + i) * 128 + ct * 16 + ln] = acc[ct][i];
    }
  }
}

// ---------------- kernel 2 (fast): edge filter -> dst-sorted bf16 msg rows ----------------
__global__ __launch_bounds__(256, 2) void edge_fast_kernel(
    const float* __restrict__ edge_attr,
    const int*   __restrict__ edge_index,
    const float* __restrict__ edge_weight,
    const float* __restrict__ W_f1, const float* __restrict__ b_f1,
    const float* __restrict__ W_f2, const float* __restrict__ b_f2,
    const float* __restrict__ h,
    int* __restrict__ cursor,
    unsigned short* __restrict__ msg)
{
  __shared__ __align__(16) unsigned short sW1t[128 * 72];
  __shared__ __align__(16) unsigned short sW2t[128 * 136];
  __shared__ __align__(16) unsigned short sT[64 * 136];
  __shared__ float sb1[128], sb2[128], sC[64];
  __shared__ int sSrc[64], sPos[64];

  const int tid = threadIdx.x, wave = tid >> 6, lane = tid & 63;
  const int ln = lane & 15, grp = lane >> 4;

  for (int idx = tid; idx < 128 * 64; idx += 256) {
    int k = idx >> 7, c = idx & 127;
    sW1t[c * 72 + k] = (k < NUM_RBF) ? f2bf(W_f1[k * 128 + c]) : (short)0;
  }
  for (int idx = tid; idx < 128 * 128; idx += 256) {
    int k = idx >> 7, c = idx & 127;
    sW2t[c * 136 + k] = f2bf(W_f2[idx]);
  }
  if (tid < 128) { sb1[tid] = b_f1[tid]; sb2[tid] = b_f2[tid]; }

  const int nTiles = N_EDGES / 64;
  for (int tile = blockIdx.x; tile < nTiles; tile += gridDim.x) {
    const int e0 = tile * 64;
    for (int idx = tid; idx < 64 * NUM_RBF; idx += 256) {
      int e = idx / NUM_RBF, k = idx - e * NUM_RBF;
      sT[e * 136 + k] = f2bf(edge_attr[(size_t)e0 * NUM_RBF + idx]);
    }
    for (int idx = tid; idx < 64 * 14; idx += 256) {
      int e = idx / 14, k = NUM_RBF + (idx - (idx / 14) * 14);
      sT[e * 136 + k] = 0;
    }
    if (tid < 64) {
      int e = e0 + tid;
      sC[tid] = 0.5f * (__cosf(edge_weight[e] * 0.31415926535f) + 1.0f);
      sSrc[tid] = edge_index[e];
      int dst = edge_index[N_EDGES + e];
      sPos[tid] = atomicAdd(&cursor[dst], 1);
    }
    __syncthreads();

    const int erow = wave * 16 + ln;
    bf16x8 a0 = *(const bf16x8*)&sT[erow * 136 + grp * 8];
    bf16x8 a1 = *(const bf16x8*)&sT[erow * 136 + 32 + grp * 8];
    __syncthreads();

    f32x4 acc[8];
#pragma unroll
    for (int ct = 0; ct < 8; ++ct) {
      f32x4 z = {0.f, 0.f, 0.f, 0.f};
      int c = ct * 16 + ln;
      bf16x8 b0 = *(const bf16x8*)&sW1t[c * 72 + grp * 8];
      bf16x8 b1 = *(const bf16x8*)&sW1t[c * 72 + 32 + grp * 8];
      z = mfma16(a0, b0, z);
      z = mfma16(a1, b1, z);
      acc[ct] = z;
    }
#pragma unroll
    for (int ct = 0; ct < 8; ++ct) {
      int c = ct * 16 + ln;
      float bias = sb1[c];
#pragma unroll
      for (int i = 0; i < 4; ++i) {
        int el = wave * 16 + grp * 4 + i;
        sT[el * 136 + c] = f2bf(fast_tanh(acc[ct][i] + bias));
      }
    }
    __syncthreads();

    bf16x8 af[4];
#pragma unroll
    for (int ks = 0; ks < 4; ++ks)
      af[ks] = *(const bf16x8*)&sT[erow * 136 + ks * 32 + grp * 8];
    f32x4 acc2[8];
#pragma unroll
    for (int ct = 0; ct < 8; ++ct) {
      f32x4 z = {0.f, 0.f, 0.f, 0.f};
      int c = ct * 16 + ln;
#pragma unroll
      for (int ks = 0; ks < 4; ++ks) {
        bf16x8 b = *(const bf16x8*)&sW2t[c * 136 + ks * 32 + grp * 8];
        z = mfma16(af[ks], b, z);
      }
      acc2[ct] = z;
    }
#pragma unroll
    for (int ct = 0; ct < 8; ++ct) {
      int c = ct * 16 + ln;
      float bias = sb2[c];
#pragma unroll
      for (int i = 0; i < 4; ++i) {
        int el = wave * 16 + grp * 4 + i;
        float wf = (acc2[ct][i] + bias) * sC[el];
        float m = h[(size_t)sSrc[el] * 128 + c] * wf;
        __builtin_nontemporal_store((unsigned short)f2bf(m),
                                    &msg[(size_t)sPos[el] * 128 + c]);
      }
    }
    __syncthreads();
  }
}

// ---------------- kernel 3 (fast): agg = segment-sum(msg) ; out = tanh(agg@W_out+b_out)@W_lin+b_lin ----------------
__global__ __launch_bounds__(256) void tail_fast_kernel(
    const int* __restrict__ row_start,
    const unsigned short* __restrict__ msg,
    const float* __restrict__ W_out, const float* __restrict__ b_out,
    const float* __restrict__ W_lin, const float* __restrict__ b_lin,
    float* __restrict__ out)
{
  __shared__ __align__(16) unsigned short sWo[128 * 136];
  __shared__ __align__(16) unsigned short sWl[128 * 136];
  __shared__ __align__(16) unsigned short sT[64 * 136];
  __shared__ float sbo[128], sbl[128];
  __shared__ int sRS[65];
  const int tid = threadIdx.x, wave = tid >> 6, lane = tid & 63;
  const int ln = lane & 15, grp = lane >> 4;
  const int r0 = blockIdx.x * 64;

  for (int idx = tid; idx < 128 * 128; idx += 256) {
    int k = idx >> 7, c = idx & 127;
    sWo[c * 136 + k] = f2bf(W_out[idx]);
    sWl[c * 136 + k] = f2bf(W_lin[idx]);
  }
  if (tid < 128) { sbo[tid] = b_out[tid]; sbl[tid] = b_lin[tid]; }
  if (tid < 65) sRS[tid] = row_start[r0 + tid];
  __syncthreads();

  // segment-sum: wave handles 16 node rows; lane covers 2 cols
  for (int j = 0; j < 16; ++j) {
    const int nl = wave * 16 + j;
    float ax = 0.f, ay = 0.f;
    const int eb = sRS[nl], ee = sRS[nl + 1];
    for (int e = eb; e < ee; ++e) {
      unsigned int u = *(const unsigned int*)&msg[(size_t)e * 128 + lane * 2];
      ax += bf2f((unsigned short)(u & 0xffff));
      ay += bf2f((unsigned short)(u >> 16));
    }
    unsigned int packed = (unsigned int)(unsigned short)f2bf(ax) |
                          ((unsigned int)(unsigned short)f2bf(ay) << 16);
    *(unsigned int*)&sT[nl * 136 + lane * 2] = packed;
  }
  __syncthreads();

  bf16x8 af[4];
#pragma unroll
  for (int ks = 0; ks < 4; ++ks)
    af[ks] = *(const bf16x8*)&sT[(wave * 16 + ln) * 136 + ks * 32 + grp * 8];
  f32x4 acc[8];
#pragma unroll
  for (int ct = 0; ct < 8; ++ct) {
    f32x4 z = {0.f, 0.f, 0.f, 0.f};
    int c = ct * 16 + ln;
#pragma unroll
    for (int ks = 0; ks < 4; ++ks) {
      bf16x8 b = *(const bf16x8*)&sWo[c * 136 + ks * 32 + grp * 8];
      z = mfma16(af[ks], b, z);
    }
    acc[ct] = z;
  }
  __syncthreads();  // done reading sT (agg); will overwrite with tanh tile
#pragma unroll
  for (int ct = 0; ct < 8; ++ct) {
    int c = ct * 16 + ln;
    float bias = sbo[c];
#pragma unroll
    for (int i = 0; i < 4; ++i) {
      int rl = wave * 16 + grp * 4 + i;
      sT[rl * 136 + c] = f2bf(fast_tanh(acc[ct][i] + bias));
    }
  }
  __syncthreads();

#pragma unroll
  for (int ks = 0; ks < 4; ++ks)
    af[ks] = *(const bf16x8*)&sT[(wave * 16 + ln) * 136 + ks * 32 + grp * 8];
  f32x4 acc2[8];
#pragma unroll
  for (int ct = 0; ct < 8; ++ct) {
    f32x4 z = {0.f, 0.f, 0.f, 0.f};
    int c = ct * 16 + ln;
#pragma unroll
    for (int ks = 0; ks < 4; ++ks) {
      bf16x8 b = *(const bf16x8*)&sWl[c * 136 + ks * 32 + grp * 8];
      z = mfma16(af[ks], b, z);
    }
    acc2[ct] = z;
  }
#pragma unroll
  for (int ct = 0; ct < 8; ++ct) {
    int c = ct * 16 + ln;
    float bias = sbl[c];
#pragma unroll
    for (int i = 0; i < 4; ++i) {
      out[(size_t)(r0 + wave * 16 + grp * 4 + i) * 128 + c] = acc2[ct][i] + bias;
    }
  }
}

// ================= fallback path (R0 atomic version) =================
__global__ __launch_bounds__(256, 2) void edge_kernel(
    const float* __restrict__ edge_attr,
    const int*   __restrict__ edge_index,
    const float* __restrict__ edge_weight,
    const float* __restrict__ W_f1, const float* __restrict__ b_f1,
    const float* __restrict__ W_f2, const float* __restrict__ b_f2,
    const float* __restrict__ h, float* __restrict__ agg)
{
  __shared__ __align__(16) unsigned short sW1t[128 * 72];
  __shared__ __align__(16) unsigned short sW2t[128 * 136];
  __shared__ __align__(16) unsigned short sT[64 * 136];
  __shared__ float sb1[128], sb2[128], sC[64];
  __shared__ int sSrc[64], sDst[64];

  const int tid = threadIdx.x, wave = tid >> 6, lane = tid & 63;
  const int ln = lane & 15, grp = lane >> 4;

  for (int idx = tid; idx < 128 * 64; idx += 256) {
    int k = idx >> 7, c = idx & 127;
    sW1t[c * 72 + k] = (k < NUM_RBF) ? f2bf(W_f1[k * 128 + c]) : (short)0;
  }
  for (int idx = tid; idx < 128 * 128; idx += 256) {
    int k = idx >> 7, c = idx & 127;
    sW2t[c * 136 + k] = f2bf(W_f2[idx]);
  }
  if (tid < 128) { sb1[tid] = b_f1[tid]; sb2[tid] = b_f2[tid]; }

  const int nTiles = N_EDGES / 64;
  for (int tile = blockIdx.x; tile < nTiles; tile += gridDim.x) {
    const int e0 = tile * 64;
    for (int idx = tid; idx < 64 * NUM_RBF; idx += 256) {
      int e = idx / NUM_RBF, k = idx - e * NUM_RBF;
      sT[e * 136 + k] = f2bf(edge_attr[(size_t)e0 * NUM_RBF + idx]);
    }
    for (int idx = tid; idx < 64 * 14; idx += 256) {
      int e = idx / 14, k = NUM_RBF + (idx - (idx / 14) * 14);
      sT[e * 136 + k] = 0;
    }
    if (tid < 64) {
      int e = e0 + tid;
      sC[tid] = 0.5f * (__cosf(edge_weight[e] * 0.31415926535f) + 1.0f);
      sSrc[tid] = edge_index[e];
      sDst[tid] = edge_index[N_EDGES + e];
    }
    __syncthreads();

    const int erow = wave * 16 + ln;
    bf16x8 a0 = *(const bf16x8*)&sT[erow * 136 + grp * 8];
    bf16x8 a1 = *(const bf16x8*)&sT[erow * 136 + 32 + grp * 8];
    __syncthreads();

    f32x4 acc[8];
#pragma unroll
    for (int ct = 0; ct < 8; ++ct) {
      f32x4 z = {0.f, 0.f, 0.f, 0.f};
      int c = ct * 16 + ln;
      bf16x8 b0 = *(const bf16x8*)&sW1t[c * 72 + grp * 8];
      bf16x8 b1 = *(const bf16x8*)&sW1t[c * 72 + 32 + grp * 8];
      z = mfma16(a0, b0, z);
      z = mfma16(a1, b1, z);
      acc[ct] = z;
    }
#pragma unroll
    for (int ct = 0; ct < 8; ++ct) {
      int c = ct * 16 + ln;
      float bias = sb1[c];
#pragma unroll
      for (int i = 0; i < 4; ++i) {
        int el = wave * 16 + grp * 4 + i;
        sT[el * 136 + c] = f2bf(fast_tanh(acc[ct][i] + bias));
      }
    }
    __syncthreads();

    bf16x8 af[4];
#pragma unroll
    for (int ks = 0; ks < 4; ++ks)
      af[ks] = *(const bf16x8*)&sT[erow * 136 + ks * 32 + grp * 8];
    f32x4 acc2[8];
#pragma unroll
    for (int ct = 0; ct < 8; ++ct) {
      f32x4 z = {0.f, 0.f, 0.f, 0.f};
      int c = ct * 16 + ln;
#pragma unroll
      for (int ks = 0; ks < 4; ++ks) {
        bf16x8 b = *(const bf16x8*)&sW2t[c * 136 + ks * 32 + grp * 8];
        z = mfma16(af[ks], b, z);
      }
      acc2[ct] = z;
    }
#pragma unroll
    for (int ct = 0; ct < 8; ++ct) {
      int c = ct * 16 + ln;
      float bias = sb2[c];
#pragma unroll
      for (int i = 0; i < 4; ++i) {
        int el = wave * 16 + grp * 4 + i;
        float wf = (acc2[ct][i] + bias) * sC[el];
        float m = h[(size_t)sSrc[el] * 128 + c] * wf;
        atomicAdd(&agg[(size_t)sDst[el] * 128 + c], m);
      }
    }
    __syncthreads();
  }
}

__global__ __launch_bounds__(256) void tail_kernel(
    const float* __restrict__ agg,
    const float* __restrict__ W_out, const float* __restrict__ b_out,
    const float* __restrict__ W_lin, const float* __restrict__ b_lin,
    float* __restrict__ out)
{
  __shared__ __align__(16) unsigned short sWo[128 * 136];
  __shared__ __align__(16) unsigned short sWl[128 * 136];
  __shared__ __align__(16) unsigned short sT[64 * 136];
  __shared__ float sbo[128], sbl[128];
  const int tid = threadIdx.x, wave = tid >> 6, lane = tid & 63;
  const int ln = lane & 15, grp = lane >> 4;
  const int r0 = blockIdx.x * 64;

  for (int idx = tid; idx < 128 * 128; idx += 256) {
    int k = idx >> 7, c = idx & 127;
    sWo[c * 136 + k] = f2bf(W_out[idx]);
    sWl[c * 136 + k] = f2bf(W_lin[idx]);
  }
  if (tid < 128) { sbo[tid] = b_out[tid]; sbl[tid] = b_lin[tid]; }
  __syncthreads();

  const size_t r = (size_t)r0 + wave * 16 + ln;
  f32x4 acc[8];
#pragma unroll
  for (int ct = 0; ct < 8; ++ct) acc[ct] = (f32x4){0.f, 0.f, 0.f, 0.f};
#pragma unroll
  for (int ks = 0; ks < 4; ++ks) {
    bf16x8 a = load8_f32_bf16(&agg[r * 128 + ks * 32 + grp * 8]);
#pragma unroll
    for (int ct = 0; ct < 8; ++ct) {
      bf16x8 b = *(const bf16x8*)&sWo[(ct * 16 + ln) * 136 + ks * 32 + grp * 8];
      acc[ct] = mfma16(a, b, acc[ct]);
    }
  }
#pragma unroll
  for (int ct = 0; ct < 8; ++ct) {
    int c = ct * 16 + ln;
    float bias = sbo[c];
#pragma unroll
    for (int i = 0; i < 4; ++i) {
      int rl = wave * 16 + grp * 4 + i;
      sT[rl * 136 + c] = f2bf(fast_tanh(acc[ct][i] + bias));
    }
  }
  __syncthreads();

  bf16x8 af[4];
#pragma unroll
  for (int ks = 0; ks < 4; ++ks)
    af[ks] = *(const bf16x8*)&sT[(wave * 16 + ln) * 136 + ks * 32 + grp * 8];
  f32x4 acc2[8];
#pragma unroll
  for (int ct = 0; ct < 8; ++ct) {
    f32x4 z = {0.f, 0.f, 0.f, 0.f};
    int c = ct * 16 + ln;
#pragma unroll
    for (int ks = 0; ks < 4; ++ks) {
      bf16x8 b = *(const bf16x8*)&sWl[c * 136 + ks * 32 + grp * 8];
      z = mfma16(af[ks], b, z);
    }
    acc2[ct] = z;
  }
#pragma unroll
  for (int ct = 0; ct < 8; ++ct) {
    int c = ct * 16 + ln;
    float bias = sbl[c];
#pragma unroll
    for (int i = 0; i < 4; ++i) {
      out[(size_t)(r0 + wave * 16 + grp * 4 + i) * 128 + c] = acc2[ct][i] + bias;
    }
  }
}

extern "C" void kernel_launch(void* const* d_in, const int* in_sizes, int n_in,
                              void* d_out, int out_size, void* d_ws, size_t ws_size,
                              hipStream_t stream) {
  const float* x     = (const float*)d_in[0];
  const int*   ei    = (const int*)d_in[1];
  const float* ew    = (const float*)d_in[2];
  const float* ea    = (const float*)d_in[3];
  const float* W_f1  = (const float*)d_in[4];
  const float* b_f1  = (const float*)d_in[5];
  const float* W_f2  = (const float*)d_in[6];
  const float* b_f2  = (const float*)d_in[7];
  const float* W_in  = (const float*)d_in[8];
  const float* W_out = (const float*)d_in[9];
  const float* b_out = (const float*)d_in[10];
  const float* W_lin = (const float*)d_in[11];
  const float* b_lin = (const float*)d_in[12];

  const size_t H_BYTES   = (size_t)N_NODES * HIDDEN * 4;       // 20.48 MB
  const size_t MSG_BYTES = (size_t)N_EDGES * HIDDEN * 2;       // 163.84 MB
  const size_t HIST_B    = (size_t)N_NODES * 4;
  const size_t RS_B      = (size_t)(N_NODES + 1) * 4 + 12;     // padded
  const size_t NEED = H_BYTES + MSG_BYTES + HIST_B + RS_B + HIST_B;

  char* ws = (char*)d_ws;
  float* h = (float*)ws;

  if (ws_size >= NEED) {
    unsigned short* msg = (unsigned short*)(ws + H_BYTES);
    int* hist      = (int*)(ws + H_BYTES + MSG_BYTES);
    int* row_start = (int*)(ws + H_BYTES + MSG_BYTES + HIST_B);
    int* cursor    = (int*)(ws + H_BYTES + MSG_BYTES + HIST_B + RS_B);

    hipMemsetAsync(hist, 0, HIST_B, stream);
    hist_kernel<<<(N_EDGES + 255) / 256, 256, 0, stream>>>(ei, hist);
    scan_kernel<<<1, 256, 0, stream>>>(hist, row_start, cursor);
    hproj_kernel<<<N_NODES / 64, 256, 0, stream>>>(x, W_in, h);
    edge_fast_kernel<<<512, 256, 0, stream>>>(ea, ei, ew, W_f1, b_f1, W_f2, b_f2,
                                              h, cursor, msg);
    tail_fast_kernel<<<N_NODES / 64, 256, 0, stream>>>(row_start, msg,
                                                       W_out, b_out, W_lin, b_lin,
                                                       (float*)d_out);
  } else {
    float* agg = (float*)(ws + H_BYTES);
    hipMemsetAsync(agg, 0, H_BYTES, stream);
    hproj_kernel<<<N_NODES / 64, 256, 0, stream>>>(x, W_in, h);
    edge_kernel<<<512, 256, 0, stream>>>(ea, ei, ew, W_f1, b_f1, W_f2, b_f2, h, agg);
    tail_kernel<<<N_NODES / 64, 256, 0, stream>>>(agg, W_out, b_out, W_lin, b_lin,
                                                  (float*)d_out);
  }
}

// Round 3
// 318.816 us; speedup vs baseline: 2.4109x; 2.4109x over previous
//
#include <hip/hip_runtime.h>
#include <hip/hip_bf16.h>

#define N_NODES 40000
#define N_EDGES 640000
#define HIDDEN  128
#define NUM_RBF 50
#define NBLK_SCAN 157  // ceil(40000/256)

typedef __attribute__((ext_vector_type(8))) short bf16x8;
typedef __attribute__((ext_vector_type(4))) float f32x4;

__device__ __forceinline__ short f2bf(float f) {
  __hip_bfloat16 h = __float2bfloat16(f);
  return (short)__builtin_bit_cast(unsigned short, h);
}
__device__ __forceinline__ float bf2f(unsigned short u) {
  unsigned int v = ((unsigned int)u) << 16;
  return __builtin_bit_cast(float, v);
}
__device__ __forceinline__ unsigned int pack2bf(float a, float b) {
  return (unsigned int)(unsigned short)f2bf(a) |
         ((unsigned int)(unsigned short)f2bf(b) << 16);
}

__device__ __forceinline__ float fast_tanh(float x) {
  float e = __expf(2.0f * x);
  return 1.0f - 2.0f * __builtin_amdgcn_rcpf(e + 1.0f);
}

__device__ __forceinline__ f32x4 mfma16(bf16x8 a, bf16x8 b, f32x4 c) {
  return __builtin_amdgcn_mfma_f32_16x16x32_bf16(a, b, c, 0, 0, 0);
}

__device__ __forceinline__ bf16x8 load8_f32_bf16(const float* p) {
  const float4 v0 = ((const float4*)p)[0];
  const float4 v1 = ((const float4*)p)[1];
  bf16x8 r;
  r[0] = f2bf(v0.x); r[1] = f2bf(v0.y); r[2] = f2bf(v0.z); r[3] = f2bf(v0.w);
  r[4] = f2bf(v1.x); r[5] = f2bf(v1.y); r[6] = f2bf(v1.z); r[7] = f2bf(v1.w);
  return r;
}

// ---------------- CSR build ----------------
__global__ __launch_bounds__(256) void hist_kernel(const int* __restrict__ ei,
                                                   int* __restrict__ hist) {
  int e = blockIdx.x * 256 + threadIdx.x;
  if (e < N_EDGES) atomicAdd(&hist[ei[N_EDGES + e]], 1);
}

__global__ __launch_bounds__(256) void scan1_kernel(const int* __restrict__ hist,
                                                    int* __restrict__ tmp,
                                                    int* __restrict__ bsum) {
  __shared__ int ls[256];
  const int t = threadIdx.x;
  const int i = blockIdx.x * 256 + t;
  int v = (i < N_NODES) ? hist[i] : 0;
  ls[t] = v;
  __syncthreads();
  for (int off = 1; off < 256; off <<= 1) {
    int u = (t >= off) ? ls[t - off] : 0;
    __syncthreads();
    ls[t] += u;
    __syncthreads();
  }
  if (i < N_NODES) tmp[i] = ls[t];          // inclusive scan within block
  if (t == 255) bsum[blockIdx.x] = ls[255]; // block total
}

__global__ __launch_bounds__(256) void scan2_kernel(const int* __restrict__ bsum,
                                                    int* __restrict__ bpfx,
                                                    int* __restrict__ row_start) {
  __shared__ int ls[256];
  const int t = threadIdx.x;
  int v = (t < NBLK_SCAN) ? bsum[t] : 0;
  ls[t] = v;
  __syncthreads();
  for (int off = 1; off < 256; off <<= 1) {
    int u = (t >= off) ? ls[t - off] : 0;
    __syncthreads();
    ls[t] += u;
    __syncthreads();
  }
  if (t < NBLK_SCAN) bpfx[t] = ls[t] - v;   // exclusive
  if (t == 255) row_start[N_NODES] = ls[255];
}

__global__ __launch_bounds__(256) void scan3_kernel(const int* __restrict__ hist,
                                                    const int* __restrict__ tmp,
                                                    const int* __restrict__ bpfx,
                                                    int* __restrict__ row_start,
                                                    int* __restrict__ cursor) {
  const int i = blockIdx.x * 256 + threadIdx.x;
  if (i < N_NODES) {
    int rs = tmp[i] - hist[i] + bpfx[blockIdx.x];
    row_start[i] = rs;
    cursor[i] = rs;
  }
}

// ---------------- kernel 1: h = x @ W_in ----------------
__global__ __launch_bounds__(256) void hproj_kernel(
    const float* __restrict__ x, const float* __restrict__ W_in,
    float* __restrict__ h)
{
  __shared__ __align__(16) unsigned short sWt[128 * 136];
  const int tid = threadIdx.x, wave = tid >> 6, lane = tid & 63;
  const int ln = lane & 15, grp = lane >> 4;
  const int r0 = blockIdx.x * 64;

  for (int idx = tid; idx < 128 * 128; idx += 256) {
    int k = idx >> 7, c = idx & 127;
    sWt[c * 136 + k] = f2bf(W_in[idx]);
  }
  __syncthreads();

  const size_t r = (size_t)r0 + wave * 16 + ln;
  f32x4 acc[8];
#pragma unroll
  for (int ct = 0; ct < 8; ++ct) acc[ct] = (f32x4){0.f, 0.f, 0.f, 0.f};
#pragma unroll
  for (int ks = 0; ks < 4; ++ks) {
    bf16x8 a = load8_f32_bf16(&x[r * 128 + ks * 32 + grp * 8]);
#pragma unroll
    for (int ct = 0; ct < 8; ++ct) {
      bf16x8 b = *(const bf16x8*)&sWt[(ct * 16 + ln) * 136 + ks * 32 + grp * 8];
      acc[ct] = mfma16(a, b, acc[ct]);
    }
  }
#pragma unroll
  for (int ct = 0; ct < 8; ++ct) {
#pragma unroll
    for (int i = 0; i < 4; ++i) {
      h[(size_t)(r0 + wave * 16 + grp * 4 + i) * 128 + ct * 16 + ln] = acc[ct][i];
    }
  }
}

// ---------------- kernel 2: edge filter -> dst-sorted bf16 msg rows ----------------
__global__ __launch_bounds__(256, 2) void edge_fast_kernel(
    const float* __restrict__ edge_attr,
    const int*   __restrict__ edge_index,
    const float* __restrict__ edge_weight,
    const float* __restrict__ W_f1, const float* __restrict__ b_f1,
    const float* __restrict__ W_f2, const float* __restrict__ b_f2,
    const float* __restrict__ h,
    int* __restrict__ cursor,
    unsigned short* __restrict__ msg)
{
  __shared__ __align__(16) unsigned short sW1t[128 * 72];
  __shared__ __align__(16) unsigned short sW2t[128 * 136];
  __shared__ __align__(16) unsigned short sT[64 * 136];
  __shared__ float sb1[128], sb2[128], sC[64];
  __shared__ int sSrc[64], sPos[64];

  const int tid = threadIdx.x, wave = tid >> 6, lane = tid & 63;
  const int ln = lane & 15, grp = lane >> 4;

  for (int idx = tid; idx < 128 * 64; idx += 256) {
    int k = idx >> 7, c = idx & 127;
    sW1t[c * 72 + k] = (k < NUM_RBF) ? f2bf(W_f1[k * 128 + c]) : (short)0;
  }
  for (int idx = tid; idx < 128 * 128; idx += 256) {
    int k = idx >> 7, c = idx & 127;
    sW2t[c * 136 + k] = f2bf(W_f2[idx]);
  }
  if (tid < 128) { sb1[tid] = b_f1[tid]; sb2[tid] = b_f2[tid]; }

  const int nTiles = N_EDGES / 64;
  for (int tile = blockIdx.x; tile < nTiles; tile += gridDim.x) {
    const int e0 = tile * 64;
    // stage edge_attr tile as bf16 via float2 loads (tile is contiguous: 1600 float2)
    for (int idx = tid; idx < 64 * 25; idx += 256) {
      int e = idx / 25, k = 2 * (idx - e * 25);
      float2 v = ((const float2*)edge_attr)[(size_t)e0 * 25 + idx];
      *(unsigned int*)&sT[e * 136 + k] = pack2bf(v.x, v.y);
    }
    for (int idx = tid; idx < 64 * 7; idx += 256) {
      int e = idx / 7, k = NUM_RBF + 2 * (idx - e * 7);
      *(unsigned int*)&sT[e * 136 + k] = 0;  // zero-pad k in [50,64)
    }
    if (tid < 64) {
      int e = e0 + tid;
      sC[tid] = 0.5f * (__cosf(edge_weight[e] * 0.31415926535f) + 1.0f);
      sSrc[tid] = edge_index[e];
      int dst = edge_index[N_EDGES + e];
      sPos[tid] = atomicAdd(&cursor[dst], 1);
    }
    __syncthreads();

    const int erow = wave * 16 + ln;
    bf16x8 a0 = *(const bf16x8*)&sT[erow * 136 + grp * 8];
    bf16x8 a1 = *(const bf16x8*)&sT[erow * 136 + 32 + grp * 8];
    __syncthreads();  // A-frags in regs before sT is overwritten

    // GEMM1: T = tanh(A @ W1 + b1)
    f32x4 acc[8];
#pragma unroll
    for (int ct = 0; ct < 8; ++ct) {
      f32x4 z = {0.f, 0.f, 0.f, 0.f};
      int c = ct * 16 + ln;
      bf16x8 b0 = *(const bf16x8*)&sW1t[c * 72 + grp * 8];
      bf16x8 b1 = *(const bf16x8*)&sW1t[c * 72 + 32 + grp * 8];
      z = mfma16(a0, b0, z);
      z = mfma16(a1, b1, z);
      acc[ct] = z;
    }
#pragma unroll
    for (int ct = 0; ct < 8; ++ct) {
      int c = ct * 16 + ln;
      float bias = sb1[c];
#pragma unroll
      for (int i = 0; i < 4; ++i) {
        int el = wave * 16 + grp * 4 + i;
        sT[el * 136 + c] = f2bf(fast_tanh(acc[ct][i] + bias));
      }
    }
    __syncthreads();

    // GEMM2: Wf = (T @ W2 + b2) * C
    bf16x8 af[4];
#pragma unroll
    for (int ks = 0; ks < 4; ++ks)
      af[ks] = *(const bf16x8*)&sT[erow * 136 + ks * 32 + grp * 8];
    f32x4 acc2[8];
#pragma unroll
    for (int ct = 0; ct < 8; ++ct) {
      f32x4 z = {0.f, 0.f, 0.f, 0.f};
      int c = ct * 16 + ln;
#pragma unroll
      for (int ks = 0; ks < 4; ++ks) {
        bf16x8 b = *(const bf16x8*)&sW2t[c * 136 + ks * 32 + grp * 8];
        z = mfma16(af[ks], b, z);
      }
      acc2[ct] = z;
    }
    __syncthreads();  // all waves finished reading sT (af in regs)

    // write Wf (bf16) back to sT for the transpose
#pragma unroll
    for (int ct = 0; ct < 8; ++ct) {
      int c = ct * 16 + ln;
      float bias = sb2[c];
#pragma unroll
      for (int i = 0; i < 4; ++i) {
        int el = wave * 16 + grp * 4 + i;
        sT[el * 136 + c] = f2bf((acc2[ct][i] + bias) * sC[el]);
      }
    }
    __syncthreads();

    // coalesced: gather h row, multiply, write msg row (256 B contiguous/row)
#pragma unroll
    for (int j = 0; j < 16; ++j) {
      int el = wave * 16 + j;
      int src = sSrc[el];
      int pos = sPos[el];
      float2 hv = *(const float2*)&h[(size_t)src * 128 + lane * 2];
      unsigned int w = *(const unsigned int*)&sT[el * 136 + lane * 2];
      float m0 = hv.x * bf2f((unsigned short)(w & 0xffff));
      float m1 = hv.y * bf2f((unsigned short)(w >> 16));
      *(unsigned int*)&msg[(size_t)pos * 128 + lane * 2] = pack2bf(m0, m1);
    }
    __syncthreads();  // protect sT/sC/sSrc/sPos before next tile staging
  }
}

// ---------------- kernel 3: agg(bf16) = segment-sum(msg), one wave per node ----------------
__global__ __launch_bounds__(256) void segsum_kernel(
    const int* __restrict__ row_start,
    const unsigned short* __restrict__ msg,
    unsigned short* __restrict__ aggb)
{
  const int node = blockIdx.x * 4 + (threadIdx.x >> 6);
  if (node >= N_NODES) return;
  const int lane = threadIdx.x & 63;
  const int eb = row_start[node], ee = row_start[node + 1];
  const int n = ee - eb;
  const unsigned int* p = (const unsigned int*)msg + (size_t)eb * 64 + lane;
  float a0 = 0.f, b0 = 0.f, a1 = 0.f, b1 = 0.f;
  int i = 0;
  for (; i + 1 < n; i += 2) {
    unsigned int u0 = p[(size_t)i * 64];
    unsigned int u1 = p[(size_t)(i + 1) * 64];
    a0 += bf2f((unsigned short)(u0 & 0xffff));
    b0 += bf2f((unsigned short)(u0 >> 16));
    a1 += bf2f((unsigned short)(u1 & 0xffff));
    b1 += bf2f((unsigned short)(u1 >> 16));
  }
  if (i < n) {
    unsigned int u0 = p[(size_t)i * 64];
    a0 += bf2f((unsigned short)(u0 & 0xffff));
    b0 += bf2f((unsigned short)(u0 >> 16));
  }
  *(unsigned int*)&aggb[(size_t)node * 128 + lane * 2] = pack2bf(a0 + a1, b0 + b1);
}

// ---------------- kernel 4: out = tanh(agg@W_out+b_out) @ W_lin + b_lin ----------------
__global__ __launch_bounds__(256) void tailg_kernel(
    const unsigned short* __restrict__ aggb,
    const float* __restrict__ W_out, const float* __restrict__ b_out,
    const float* __restrict__ W_lin, const float* __restrict__ b_lin,
    float* __restrict__ out)
{
  __shared__ __align__(16) unsigned short sWo[128 * 136];
  __shared__ __align__(16) unsigned short sWl[128 * 136];
  __shared__ __align__(16) unsigned short sT[64 * 136];
  __shared__ float sbo[128], sbl[128];
  const int tid = threadIdx.x, wave = tid >> 6, lane = tid & 63;
  const int ln = lane & 15, grp = lane >> 4;
  const int r0 = blockIdx.x * 64;

  for (int idx = tid; idx < 128 * 128; idx += 256) {
    int k = idx >> 7, c = idx & 127;
    sWo[c * 136 + k] = f2bf(W_out[idx]);
    sWl[c * 136 + k] = f2bf(W_lin[idx]);
  }
  if (tid < 128) { sbo[tid] = b_out[tid]; sbl[tid] = b_lin[tid]; }
  __syncthreads();

  const size_t r = (size_t)r0 + wave * 16 + ln;
  bf16x8 af[4];
#pragma unroll
  for (int ks = 0; ks < 4; ++ks)
    af[ks] = *(const bf16x8*)&aggb[r * 128 + ks * 32 + grp * 8];
  f32x4 acc[8];
#pragma unroll
  for (int ct = 0; ct < 8; ++ct) {
    f32x4 z = {0.f, 0.f, 0.f, 0.f};
    int c = ct * 16 + ln;
#pragma unroll
    for (int ks = 0; ks < 4; ++ks) {
      bf16x8 b = *(const bf16x8*)&sWo[c * 136 + ks * 32 + grp * 8];
      z = mfma16(af[ks], b, z);
    }
    acc[ct] = z;
  }
#pragma unroll
  for (int ct = 0; ct < 8; ++ct) {
    int c = ct * 16 + ln;
    float bias = sbo[c];
#pragma unroll
    for (int i = 0; i < 4; ++i) {
      int rl = wave * 16 + grp * 4 + i;
      sT[rl * 136 + c] = f2bf(fast_tanh(acc[ct][i] + bias));
    }
  }
  __syncthreads();

#pragma unroll
  for (int ks = 0; ks < 4; ++ks)
    af[ks] = *(const bf16x8*)&sT[(wave * 16 + ln) * 136 + ks * 32 + grp * 8];
  f32x4 acc2[8];
#pragma unroll
  for (int ct = 0; ct < 8; ++ct) {
    f32x4 z = {0.f, 0.f, 0.f, 0.f};
    int c = ct * 16 + ln;
#pragma unroll
    for (int ks = 0; ks < 4; ++ks) {
      bf16x8 b = *(const bf16x8*)&sWl[c * 136 + ks * 32 + grp * 8];
      z = mfma16(af[ks], b, z);
    }
    acc2[ct] = z;
  }
#pragma unroll
  for (int ct = 0; ct < 8; ++ct) {
    int c = ct * 16 + ln;
    float bias = sbl[c];
#pragma unroll
    for (int i = 0; i < 4; ++i) {
      out[(size_t)(r0 + wave * 16 + grp * 4 + i) * 128 + c] = acc2[ct][i] + bias;
    }
  }
}

// ================= fallback path (atomic version) =================
__global__ __launch_bounds__(256, 2) void edge_kernel(
    const float* __restrict__ edge_attr,
    const int*   __restrict__ edge_index,
    const float* __restrict__ edge_weight,
    const float* __restrict__ W_f1, const float* __restrict__ b_f1,
    const float* __restrict__ W_f2, const float* __restrict__ b_f2,
    const float* __restrict__ h, float* __restrict__ agg)
{
  __shared__ __align__(16) unsigned short sW1t[128 * 72];
  __shared__ __align__(16) unsigned short sW2t[128 * 136];
  __shared__ __align__(16) unsigned short sT[64 * 136];
  __shared__ float sb1[128], sb2[128], sC[64];
  __shared__ int sSrc[64], sDst[64];

  const int tid = threadIdx.x, wave = tid >> 6, lane = tid & 63;
  const int ln = lane & 15, grp = lane >> 4;

  for (int idx = tid; idx < 128 * 64; idx += 256) {
    int k = idx >> 7, c = idx & 127;
    sW1t[c * 72 + k] = (k < NUM_RBF) ? f2bf(W_f1[k * 128 + c]) : (short)0;
  }
  for (int idx = tid; idx < 128 * 128; idx += 256) {
    int k = idx >> 7, c = idx & 127;
    sW2t[c * 136 + k] = f2bf(W_f2[idx]);
  }
  if (tid < 128) { sb1[tid] = b_f1[tid]; sb2[tid] = b_f2[tid]; }

  const int nTiles = N_EDGES / 64;
  for (int tile = blockIdx.x; tile < nTiles; tile += gridDim.x) {
    const int e0 = tile * 64;
    for (int idx = tid; idx < 64 * NUM_RBF; idx += 256) {
      int e = idx / NUM_RBF, k = idx - e * NUM_RBF;
      sT[e * 136 + k] = f2bf(edge_attr[(size_t)e0 * NUM_RBF + idx]);
    }
    for (int idx = tid; idx < 64 * 14; idx += 256) {
      int e = idx / 14, k = NUM_RBF + (idx - (idx / 14) * 14);
      sT[e * 136 + k] = 0;
    }
    if (tid < 64) {
      int e = e0 + tid;
      sC[tid] = 0.5f * (__cosf(edge_weight[e] * 0.31415926535f) + 1.0f);
      sSrc[tid] = edge_index[e];
      sDst[tid] = edge_index[N_EDGES + e];
    }
    __syncthreads();

    const int erow = wave * 16 + ln;
    bf16x8 a0 = *(const bf16x8*)&sT[erow * 136 + grp * 8];
    bf16x8 a1 = *(const bf16x8*)&sT[erow * 136 + 32 + grp * 8];
    __syncthreads();

    f32x4 acc[8];
#pragma unroll
    for (int ct = 0; ct < 8; ++ct) {
      f32x4 z = {0.f, 0.f, 0.f, 0.f};
      int c = ct * 16 + ln;
      bf16x8 b0 = *(const bf16x8*)&sW1t[c * 72 + grp * 8];
      bf16x8 b1 = *(const bf16x8*)&sW1t[c * 72 + 32 + grp * 8];
      z = mfma16(a0, b0, z);
      z = mfma16(a1, b1, z);
      acc[ct] = z;
    }
#pragma unroll
    for (int ct = 0; ct < 8; ++ct) {
      int c = ct * 16 + ln;
      float bias = sb1[c];
#pragma unroll
      for (int i = 0; i < 4; ++i) {
        int el = wave * 16 + grp * 4 + i;
        sT[el * 136 + c] = f2bf(fast_tanh(acc[ct][i] + bias));
      }
    }
    __syncthreads();

    bf16x8 af[4];
#pragma unroll
    for (int ks = 0; ks < 4; ++ks)
      af[ks] = *(const bf16x8*)&sT[erow * 136 + ks * 32 + grp * 8];
    f32x4 acc2[8];
#pragma unroll
    for (int ct = 0; ct < 8; ++ct) {
      f32x4 z = {0.f, 0.f, 0.f, 0.f};
      int c = ct * 16 + ln;
#pragma unroll
      for (int ks = 0; ks < 4; ++ks) {
        bf16x8 b = *(const bf16x8*)&sW2t[c * 136 + ks * 32 + grp * 8];
        z = mfma16(af[ks], b, z);
      }
      acc2[ct] = z;
    }
#pragma unroll
    for (int ct = 0; ct < 8; ++ct) {
      int c = ct * 16 + ln;
      float bias = sb2[c];
#pragma unroll
      for (int i = 0; i < 4; ++i) {
        int el = wave * 16 + grp * 4 + i;
        float wf = (acc2[ct][i] + bias) * sC[el];
        float m = h[(size_t)sSrc[el] * 128 + c] * wf;
        atomicAdd(&agg[(size_t)sDst[el] * 128 + c], m);
      }
    }
    __syncthreads();
  }
}

__global__ __launch_bounds__(256) void tail_kernel(
    const float* __restrict__ agg,
    const float* __restrict__ W_out, const float* __restrict__ b_out,
    const float* __restrict__ W_lin, const float* __restrict__ b_lin,
    float* __restrict__ out)
{
  __shared__ __align__(16) unsigned short sWo[128 * 136];
  __shared__ __align__(16) unsigned short sWl[128 * 136];
  __shared__ __align__(16) unsigned short sT[64 * 136];
  __shared__ float sbo[128], sbl[128];
  const int tid = threadIdx.x, wave = tid >> 6, lane = tid & 63;
  const int ln = lane & 15, grp = lane >> 4;
  const int r0 = blockIdx.x * 64;

  for (int idx = tid; idx < 128 * 128; idx += 256) {
    int k = idx >> 7, c = idx & 127;
    sWo[c * 136 + k] = f2bf(W_out[idx]);
    sWl[c * 136 + k] = f2bf(W_lin[idx]);
  }
  if (tid < 128) { sbo[tid] = b_out[tid]; sbl[tid] = b_lin[tid]; }
  __syncthreads();

  const size_t r = (size_t)r0 + wave * 16 + ln;
  f32x4 acc[8];
#pragma unroll
  for (int ct = 0; ct < 8; ++ct) acc[ct] = (f32x4){0.f, 0.f, 0.f, 0.f};
#pragma unroll
  for (int ks = 0; ks < 4; ++ks) {
    bf16x8 a = load8_f32_bf16(&agg[r * 128 + ks * 32 + grp * 8]);
#pragma unroll
    for (int ct = 0; ct < 8; ++ct) {
      bf16x8 b = *(const bf16x8*)&sWo[(ct * 16 + ln) * 136 + ks * 32 + grp * 8];
      acc[ct] = mfma16(a, b, acc[ct]);
    }
  }
#pragma unroll
  for (int ct = 0; ct < 8; ++ct) {
    int c = ct * 16 + ln;
    float bias = sbo[c];
#pragma unroll
    for (int i = 0; i < 4; ++i) {
      int rl = wave * 16 + grp * 4 + i;
      sT[rl * 136 + c] = f2bf(fast_tanh(acc[ct][i] + bias));
    }
  }
  __syncthreads();

  bf16x8 af[4];
#pragma unroll
  for (int ks = 0; ks < 4; ++ks)
    af[ks] = *(const bf16x8*)&sT[(wave * 16 + ln) * 136 + ks * 32 + grp * 8];
  f32x4 acc2[8];
#pragma unroll
  for (int ct = 0; ct < 8; ++ct) {
    f32x4 z = {0.f, 0.f, 0.f, 0.f};
    int c = ct * 16 + ln;
#pragma unroll
    for (int ks = 0; ks < 4; ++ks) {
      bf16x8 b = *(const bf16x8*)&sWl[c * 136 + ks * 32 + grp * 8];
      z = mfma16(af[ks], b, z);
    }
    acc2[ct] = z;
  }
#pragma unroll
  for (int ct = 0; ct < 8; ++ct) {
    int c = ct * 16 + ln;
    float bias = sbl[c];
#pragma unroll
    for (int i = 0; i < 4; ++i) {
      out[(size_t)(r0 + wave * 16 + grp * 4 + i) * 128 + c] = acc2[ct][i] + bias;
    }
  }
}

extern "C" void kernel_launch(void* const* d_in, const int* in_sizes, int n_in,
                              void* d_out, int out_size, void* d_ws, size_t ws_size,
                              hipStream_t stream) {
  const float* x     = (const float*)d_in[0];
  const int*   ei    = (const int*)d_in[1];
  const float* ew    = (const float*)d_in[2];
  const float* ea    = (const float*)d_in[3];
  const float* W_f1  = (const float*)d_in[4];
  const float* b_f1  = (const float*)d_in[5];
  const float* W_f2  = (const float*)d_in[6];
  const float* b_f2  = (const float*)d_in[7];
  const float* W_in  = (const float*)d_in[8];
  const float* W_out = (const float*)d_in[9];
  const float* b_out = (const float*)d_in[10];
  const float* W_lin = (const float*)d_in[11];
  const float* b_lin = (const float*)d_in[12];

  const size_t H_BYTES   = (size_t)N_NODES * HIDDEN * 4;   // 20.48 MB
  const size_t MSG_BYTES = (size_t)N_EDGES * HIDDEN * 2;   // 163.84 MB
  const size_t I_B       = (size_t)N_NODES * 4;            // 160 KB
  const size_t RS_B      = ((size_t)(N_NODES + 1) * 4 + 15) & ~(size_t)15;
  const size_t SB_B      = 1024;                           // bsum/bpfx padded
  const size_t NEED = H_BYTES + MSG_BYTES + I_B /*hist*/ + RS_B + I_B /*cursor*/ +
                      I_B /*tmp*/ + SB_B + SB_B;

  char* ws = (char*)d_ws;
  float* h = (float*)ws;

  if (ws_size >= NEED) {
    char* q = ws + H_BYTES;
    unsigned short* msg = (unsigned short*)q;  q += MSG_BYTES;
    int* hist      = (int*)q;                  q += I_B;
    int* row_start = (int*)q;                  q += RS_B;
    int* cursor    = (int*)q;                  q += I_B;
    int* tmp       = (int*)q;                  q += I_B;
    int* bsum      = (int*)q;                  q += SB_B;
    int* bpfx      = (int*)q;
    unsigned short* aggb = (unsigned short*)h;  // aliases h: h dead after edge

    hipMemsetAsync(hist, 0, I_B, stream);
    hist_kernel<<<(N_EDGES + 255) / 256, 256, 0, stream>>>(ei, hist);
    scan1_kernel<<<NBLK_SCAN, 256, 0, stream>>>(hist, tmp, bsum);
    scan2_kernel<<<1, 256, 0, stream>>>(bsum, bpfx, row_start);
    scan3_kernel<<<NBLK_SCAN, 256, 0, stream>>>(hist, tmp, bpfx, row_start, cursor);
    hproj_kernel<<<N_NODES / 64, 256, 0, stream>>>(x, W_in, h);
    edge_fast_kernel<<<512, 256, 0, stream>>>(ea, ei, ew, W_f1, b_f1, W_f2, b_f2,
                                              h, cursor, msg);
    segsum_kernel<<<N_NODES / 4, 256, 0, stream>>>(row_start, msg, aggb);
    tailg_kernel<<<N_NODES / 64, 256, 0, stream>>>(aggb, W_out, b_out,
                                                   W_lin, b_lin, (float*)d_out);
  } else {
    float* agg = (float*)(ws + H_BYTES);
    hipMemsetAsync(agg, 0, H_BYTES, stream);
    hproj_kernel<<<N_NODES / 64, 256, 0, stream>>>(x, W_in, h);
    edge_kernel<<<512, 256, 0, stream>>>(ea, ei, ew, W_f1, b_f1, W_f2, b_f2, h, agg);
    tail_kernel<<<N_NODES / 64, 256, 0, stream>>>(agg, W_out, b_out, W_lin, b_lin,
                                                  (float*)d_out);
  }
}